// Round 13
// baseline (225.586 us; speedup 1.0000x reference)
//
#include <hip/hip_runtime.h>
#include <math.h>

#define EPSF 1e-8f

typedef _Float16 f16x8 __attribute__((ext_vector_type(8)));
typedef float f32x4 __attribute__((ext_vector_type(4)));

#define GLOAD_LDS16(g, l)                                                      \
  __builtin_amdgcn_global_load_lds(                                            \
      (const __attribute__((address_space(1))) unsigned int*)(g),              \
      (__attribute__((address_space(3))) unsigned int*)(l), 16, 0, 0)

#define WAITV(n) asm volatile("s_waitcnt vmcnt(" #n ")" ::: "memory")
#define BAR() __builtin_amdgcn_s_barrier()

__device__ __forceinline__ unsigned int ord_from_float(float f) {
  unsigned int u = __float_as_uint(f);
  return (u & 0x80000000u) ? ~u : (u | 0x80000000u);
}

__device__ __forceinline__ float float_from_ord(unsigned int o) {
  return (o & 0x80000000u) ? __uint_as_float(o & 0x7fffffffu)
                           : __uint_as_float(~o);
}

__device__ __forceinline__ unsigned long long shfl_xor_u64(unsigned long long x, int m) {
  int lo = __shfl_xor((int)(unsigned int)(x & 0xffffffffull), m, 64);
  int hi = __shfl_xor((int)(unsigned int)(x >> 32), m, 64);
  return ((unsigned long long)(unsigned int)hi << 32) | (unsigned int)lo;
}

// ---------------- merged prep kernel ----------------
__global__ __launch_bounds__(64) void prep_kernel(
    const float* __restrict__ inp, const float* __restrict__ tgt,
    _Float16* __restrict__ Acat, _Float16* __restrict__ Bcat,
    float* __restrict__ s_in, float* __restrict__ s_st,
    int N, int M, int Npad, int Mpad, int D, int DP, int KPA) {
  const int r = blockIdx.x;
  if (r < Npad) {
    _Float16* row = Acat + (size_t)r * KPA;
    float s = 0.f;
    for (int d = threadIdx.x; d < DP; d += 64) {
      float lg = 0.f;
      if (r < N && d < D) {
        float x = inp[(size_t)r * D + d];
        s += x;
        lg = logf(x + EPSF);
      }
      _Float16 h = (_Float16)lg;
      _Float16 l = (_Float16)(lg - (float)h);
      row[d] = h;
      row[DP + d] = h;
      row[2 * DP + d] = l;
    }
    #pragma unroll
    for (int m = 1; m < 64; m <<= 1) s += __shfl_xor(s, m, 64);
    if (threadIdx.x == 0 && r < N) s_in[r] = s;
  }
  if (r < Mpad) {
    _Float16* row = Bcat + (size_t)r * KPA;
    float s = 0.f;
    for (int d = threadIdx.x; d < DP; d += 64) {
      float x = 0.f;
      if (r < M && d < D) {
        x = tgt[(size_t)r * D + d];
        if (x > 1.0f)
          s += x * logf(x) - x + 0.5f * logf(6.283185307179586f * x);
      }
      _Float16 h = (_Float16)x;
      _Float16 l = (_Float16)(x - (float)h);
      row[d] = h;
      row[DP + d] = l;
      row[2 * DP + d] = h;
    }
    #pragma unroll
    for (int m = 1; m < 64; m <<= 1) s += __shfl_xor(s, m, 64);
    if (threadIdx.x == 0 && r < M) s_st[r] = s;
  }
}

// ---------------- MFMA pair-min kernel (r6 core, verified) ----------------
// Epilogue: per-wave min over rl -> LDS combine across the 4 wc-waves ->
// single unique store per (bcol,row). No atomics, deterministic.
#define BT 256
#define BUFH 8192  // halves per buffer per operand (256 rows x 32 halves = 16 KB)

__global__ __launch_bounds__(512, 2) void mfma_pair_min_kernel(
    const _Float16* __restrict__ Acat, const _Float16* __restrict__ Bcat,
    const float* __restrict__ s_st, unsigned long long* __restrict__ packed2,
    int N, int M, int KPA, int gx, int Npad) {
  extern __shared__ __align__(16) _Float16 smem[];
  _Float16* const AshB = smem;              // 4 * BUFH
  _Float16* const BshB = smem + 4 * BUFH;   // 4 * BUFH

  const int t = threadIdx.x;
  const int lane = t & 63;
  const int wid = t >> 6;          // 0..7
  const int wr = wid >> 2;         // 0..1  -> 128 output rows
  const int wc = wid & 3;          // 0..3  -> 64 output cols

  // XCD chunking + column-major traversal inside each chunk (round-6 verified)
  const int nwg = gridDim.x;
  const int q8 = nwg >> 3;
  const int xcd = blockIdx.x & 7;
  const int i8 = blockIdx.x >> 3;
  int brow, bcol;
  if (q8 % gx == 0) {
    int bh = q8 / gx;              // row-bands per chunk
    brow = xcd * bh + i8 % bh;
    bcol = i8 / bh;
  } else {
    int wg = xcd * q8 + i8;
    brow = wg / gx;
    bcol = wg % gx;
  }
  const int row0 = brow * BT;
  const int col0 = bcol * BT;

  f32x4 acc[8][4] = {};

  // Staging (round-3/4 verified swizzle): LDS dest linear; global source slot
  // pre-swizzled: LDS(r,s) = global(r, s^((r>>1)&3)). 0 bank conflicts.
  const int srow = lane >> 2;
  const int gs = (lane & 3) ^ ((lane >> 3) & 3);
  const _Float16* a0 = Acat + (size_t)(row0 + wid * 32 + srow) * KPA + gs * 8;
  const _Float16* a1 = a0 + (size_t)16 * KPA;
  const _Float16* b0 = Bcat + (size_t)(col0 + wid * 32 + srow) * KPA + gs * 8;
  const _Float16* b1 = b0 + (size_t)16 * KPA;

#define STAGE(buf, step)                                                       \
  do {                                                                         \
    const int so_ = (step) * 32;                                               \
    GLOAD_LDS16(a0 + so_, AshB + wid * 1024 + (buf) * BUFH);                   \
    GLOAD_LDS16(a1 + so_, AshB + wid * 1024 + (buf) * BUFH + 512);             \
    GLOAD_LDS16(b0 + so_, BshB + wid * 1024 + (buf) * BUFH);                   \
    GLOAD_LDS16(b1 + so_, BshB + wid * 1024 + (buf) * BUFH + 512);             \
  } while (0)

  const int rl = lane & 15;
  const int qq = lane >> 4;
  const int sa = qq ^ ((rl >> 1) & 3);  // swizzled slot

#define COMPUTE(buf)                                                           \
  do {                                                                         \
    const int bofs_ = (buf) * BUFH;                                            \
    f16x8 af[8], bf[4];                                                        \
    _Pragma("unroll")                                                          \
    for (int m = 0; m < 8; ++m)                                                \
      af[m] = *(const f16x8*)(&AshB[bofs_ + (wr * 128 + m * 16 + rl) * 32 + sa * 8]); \
    _Pragma("unroll")                                                          \
    for (int n = 0; n < 4; ++n)                                                \
      bf[n] = *(const f16x8*)(&BshB[bofs_ + (wc * 64 + n * 16 + rl) * 32 + sa * 8]); \
    __builtin_amdgcn_s_setprio(1);                                             \
    _Pragma("unroll")                                                          \
    for (int m = 0; m < 8; ++m)                                                \
      _Pragma("unroll")                                                        \
      for (int n = 0; n < 4; ++n)                                              \
        acc[m][n] = __builtin_amdgcn_mfma_f32_16x16x32_f16(af[m], bf[n],       \
                                                           acc[m][n], 0, 0, 0); \
    __builtin_amdgcn_s_setprio(0);                                             \
  } while (0)

  const int NT = KPA >> 5;  // 18 for D=180

  // prologue: stage steps 0,1,2; wait for step 0 (8 newer loads in flight)
  STAGE(0, 0);
  STAGE(1, 1);
  STAGE(2, 2);
  WAITV(8);
  BAR();

  int kt = 0;
  for (; kt < NT - 3; ++kt) {
    STAGE((kt + 3) & 3, kt + 3);  // depth-3 prefetch
    COMPUTE(kt & 3);
    WAITV(8);                     // oldest stage (kt+1) landed; 8 stay in flight
    BAR();
  }
  COMPUTE(kt & 3);  // NT-3
  WAITV(4);
  BAR();
  ++kt;
  COMPUTE(kt & 3);  // NT-2
  WAITV(0);
  BAR();
  ++kt;
  COMPUTE(kt & 3);  // NT-1

#undef STAGE
#undef COMPUTE

  // ---- fused min/argmin epilogue ----
  // C/D frag: col = lane&15, row = (lane>>4)*4 + reg   [guide §3, m89-verified]
  // Stage 1: per-wave min over its 16 rl-lanes (covers the wave's 64-col slice).
  // Stage 2: LDS combine across the 4 wc-waves sharing each row (the bug fixed
  //          from round 12: plain stores raced across wc).
  float stv[4];
  #pragma unroll
  for (int n = 0; n < 4; ++n) {
    int gj = col0 + wc * 64 + n * 16 + rl;
    stv[n] = (gj < M) ? s_st[gj] : __builtin_inff();
  }

  __syncthreads();  // all GEMM LDS reads done -> smem reusable
  unsigned long long* red = (unsigned long long*)smem;  // [4][256] = 8 KiB

  #pragma unroll
  for (int m = 0; m < 8; ++m) {
    #pragma unroll
    for (int g = 0; g < 4; ++g) {
      unsigned long long bst = ~0ull;
      #pragma unroll
      for (int n = 0; n < 4; ++n) {
        int gj = col0 + wc * 64 + n * 16 + rl;
        float val = stv[n] - acc[m][n][g];
        unsigned long long p =
            ((unsigned long long)ord_from_float(val) << 32) | (unsigned int)gj;
        if (p < bst) bst = p;
      }
      #pragma unroll
      for (int mm = 1; mm < 16; mm <<= 1) {
        unsigned long long o = shfl_xor_u64(bst, mm);
        if (o < bst) bst = o;
      }
      if (rl == 0)
        red[wc * 256 + wr * 128 + m * 16 + qq * 4 + g] = bst;
    }
  }
  __syncthreads();

  if (t < 256) {
    int grow = row0 + t;
    if (grow < N) {
      unsigned long long b0 = red[t];
      unsigned long long b1 = red[256 + t];
      unsigned long long b2 = red[512 + t];
      unsigned long long b3 = red[768 + t];
      unsigned long long best = b0 < b1 ? b0 : b1;
      if (b2 < best) best = b2;
      if (b3 < best) best = b3;
      packed2[(size_t)bcol * Npad + grow] = best;  // unique writer -> no atomic
    }
  }
}

// ---------------- reduce: per-row min over gx col-tiles + deterministic mean ----
__global__ __launch_bounds__(256) void reduce_kernel(
    const unsigned long long* __restrict__ packed2,
    const float* __restrict__ s_in, float* __restrict__ out,
    unsigned long long* __restrict__ sumbuf, int N, int Npad, int gx) {
  int i = blockIdx.x * 256 + threadIdx.x;
  double local = 0.0;
  if (i < N) {
    unsigned long long best = ~0ull;
    for (int c = 0; c < gx; ++c) {
      unsigned long long p = packed2[(size_t)c * Npad + i];
      if (p < best) best = p;
    }
    out[1 + i] = (float)(unsigned int)(best & 0xffffffffull);
    float val = float_from_ord((unsigned int)(best >> 32));
    local = (double)(s_in[i] + val);
  }
  __shared__ double sh[256];
  sh[threadIdx.x] = local;
  __syncthreads();
  for (int o = 128; o > 0; o >>= 1) {
    if (threadIdx.x < o) sh[threadIdx.x] += sh[threadIdx.x + o];
    __syncthreads();
  }
  if (threadIdx.x == 0) {
    // fixed-point (x2^20) integer add: order-independent -> deterministic
    long long q = __double2ll_rn(sh[0] * 1048576.0);
    atomicAdd(sumbuf, (unsigned long long)q);
  }
}

__global__ void final_kernel(const unsigned long long* __restrict__ sumbuf,
                             float* __restrict__ out, int N) {
  if (threadIdx.x == 0)
    out[0] = (float)(((double)(long long)sumbuf[0] / 1048576.0) / (double)N);
}

extern "C" void kernel_launch(void* const* d_in, const int* in_sizes, int n_in,
                              void* d_out, int out_size, void* d_ws, size_t ws_size,
                              hipStream_t stream) {
  const float* inp = (const float*)d_in[0];
  const float* tgt = (const float*)d_in[1];
  float* out = (float*)d_out;

  int N = out_size - 1;  // outputs: [loss scalar, match[N]]
  int D = in_sizes[0] / N;
  int M = in_sizes[1] / D;

  int Npad = ((N + BT - 1) / BT) * BT;
  int Mpad = ((M + BT - 1) / BT) * BT;
  int DP = ((D + 31) / 32) * 32;
  int KPA = ((3 * DP + 31) / 32) * 32;  // 576 for D=180 -> 18 k-steps
  int gx = Mpad / BT, gy = Npad / BT;

  char* ws = (char*)d_ws;
  size_t off = 0;
  float* s_in = (float*)(ws + off); off += (size_t)N * 4;
  float* s_st = (float*)(ws + off); off += (size_t)M * 4;
  off = (off + 15) & ~(size_t)15;
  unsigned long long* sumbuf = (unsigned long long*)(ws + off); off += 16;
  unsigned long long* packed2 = (unsigned long long*)(ws + off);
  off += (size_t)gx * Npad * 8;
  _Float16* Acat = (_Float16*)(ws + off); off += (size_t)Npad * KPA * 2;
  _Float16* Bcat = (_Float16*)(ws + off); off += (size_t)Mpad * KPA * 2;

  hipMemsetAsync(sumbuf, 0, 8, stream);

  int pgrid = Npad > Mpad ? Npad : Mpad;
  prep_kernel<<<pgrid, 64, 0, stream>>>(inp, tgt, Acat, Bcat, s_in, s_st,
                                        N, M, Npad, Mpad, D, DP, KPA);

  const int ldsBytes = 8 * BUFH * 2;  // 128 KiB
  hipFuncSetAttribute((const void*)mfma_pair_min_kernel,
                      hipFuncAttributeMaxDynamicSharedMemorySize, ldsBytes);
  mfma_pair_min_kernel<<<gx * gy, 512, ldsBytes, stream>>>(
      Acat, Bcat, s_st, packed2, N, M, KPA, gx, Npad);

  reduce_kernel<<<(N + 255) / 256, 256, 0, stream>>>(packed2, s_in, out,
                                                     sumbuf, N, Npad, gx);
  final_kernel<<<1, 64, 0, stream>>>(sumbuf, out, N);
}